// Round 2
// baseline (153.825 us; speedup 1.0000x reference)
//
#include <hip/hip_runtime.h>
#include <hip/hip_bf16.h>

typedef unsigned short u16;
typedef unsigned int u32;
typedef __attribute__((ext_vector_type(8))) short bf16x8;   // 8 bf16 = 4 VGPR
typedef __attribute__((ext_vector_type(16))) float f32x16;  // 32x32 C/D frag
typedef __attribute__((ext_vector_type(2))) unsigned int u32x2;
typedef _Float16 h16x2 __attribute__((ext_vector_type(2)));

static __device__ __forceinline__ u16 f2bf(float f) {
    __hip_bfloat16 b = __float2bfloat16(f);   // RNE
    return *(u16*)&b;
}
static __device__ __forceinline__ u16 f2h(float f) {
    _Float16 h = (_Float16)f;                  // RNE
    return __builtin_bit_cast(u16, h);
}

// ---------------------------------------------------------------------------
// TELEMETRY ROUND: pipeline is byte-identical to R1 except edge_mlp is
// launched TWICE (idempotent). T_edge = dur_us - 122.75, and if T_edge>44us
// the edge dispatches outrank the poison fills in the rocprof top-5, exposing
// its counters for the first time.
// ---------------------------------------------------------------------------

// ---------------------------------------------------------------------------
// Kernel 0: build W1's MFMA fragment table (node-independent) + W2 as fp16.
// ---------------------------------------------------------------------------
__global__ __launch_bounds__(256) void build_wfrag(
    const float* __restrict__ W1, const float* __restrict__ W2,
    u16* __restrict__ wtab)
{
    const int flat = blockIdx.x * 256 + threadIdx.x;
    if (flat < 8192) {
        const int j    = flat & 7;
        const int lane = (flat >> 3) & 63;
        const int ks   = (flat >> 9) & 3;
        const int ct   = flat >> 11;
        const int k = ks * 16 + (lane >> 5) * 8 + j;
        const int c = ct * 32 + (lane & 31);
        const float v = (c < 64) ? W1[(size_t)k * 64 + c]
                                 : W1[(size_t)(64 + k) * 64 + (c - 64)];
        wtab[flat] = f2bf(v);
    } else if (flat < 8256) {
        wtab[flat] = f2h(W2[flat - 8192]);     // w2tab
    }
}

// ---------------------------------------------------------------------------
// Kernel A (MFMA, swapped operands): pq[n][c], c in 0..127 (fp16).
// ---------------------------------------------------------------------------
__global__ __launch_bounds__(256) void node_mfma(
    const float* __restrict__ z, const u16* __restrict__ wtab,
    const float* __restrict__ b1, u16* __restrict__ pq, int nNodes)
{
    const int lane   = threadIdx.x & 63;
    const int wave   = threadIdx.x >> 6;
    const int l31    = lane & 31;
    const int half   = lane >> 5;
    const int nodeBase = (blockIdx.x * 4 + wave) * 32;
    if (nodeBase >= nNodes) return;

    __shared__ u16 tile[4][4096];              // 8 KB per wave, wave-private

    const bf16x8* wt = (const bf16x8*)wtab;
    bf16x8 Wf[4][4];
#pragma unroll
    for (int ct = 0; ct < 4; ++ct)
#pragma unroll
        for (int ks = 0; ks < 4; ++ks)
            Wf[ct][ks] = wt[(ct * 4 + ks) * 64 + lane];

    int zrowi = nodeBase + l31;
    if (zrowi > nNodes - 1) zrowi = nNodes - 1;       // clamp (safe redundant)
    const float* zrow = z + (size_t)zrowi * 64;
    bf16x8 Zf[4];
#pragma unroll
    for (int ks = 0; ks < 4; ++ks) {
        const float4 v0 = *(const float4*)(zrow + ks * 16 + half * 8);
        const float4 v1 = *(const float4*)(zrow + ks * 16 + half * 8 + 4);
        Zf[ks][0] = (short)f2bf(v0.x); Zf[ks][1] = (short)f2bf(v0.y);
        Zf[ks][2] = (short)f2bf(v0.z); Zf[ks][3] = (short)f2bf(v0.w);
        Zf[ks][4] = (short)f2bf(v1.x); Zf[ks][5] = (short)f2bf(v1.y);
        Zf[ks][6] = (short)f2bf(v1.z); Zf[ks][7] = (short)f2bf(v1.w);
    }

    f32x16 acc[4];
#pragma unroll
    for (int ct = 0; ct < 2; ++ct)
#pragma unroll
        for (int g = 0; g < 4; ++g) {
            const float4 bv = *(const float4*)(b1 + ct * 32 + g * 8 + half * 4);
            acc[ct][4 * g + 0] = bv.x; acc[ct][4 * g + 1] = bv.y;
            acc[ct][4 * g + 2] = bv.z; acc[ct][4 * g + 3] = bv.w;
        }
    acc[2] = (f32x16)(0.0f);
    acc[3] = (f32x16)(0.0f);

#pragma unroll
    for (int ks = 0; ks < 4; ++ks)
#pragma unroll
        for (int ct = 0; ct < 4; ++ct)
            acc[ct] = __builtin_amdgcn_mfma_f32_32x32x16_bf16(
                Wf[ct][ks], Zf[ks], acc[ct], 0, 0, 0);

    char* tb = (char*)&tile[wave][0];
#pragma unroll
    for (int ct = 0; ct < 4; ++ct)
#pragma unroll
        for (int g = 0; g < 4; ++g) {
            const u32 lo = (u32)f2h(acc[ct][4 * g + 0]) |
                           ((u32)f2h(acc[ct][4 * g + 1]) << 16);
            const u32 hi = (u32)f2h(acc[ct][4 * g + 2]) |
                           ((u32)f2h(acc[ct][4 * g + 3]) << 16);
            const int roff = (ct * 64 + g * 16 + half * 8) ^ ((l31 & 7) << 4);
            *(u32x2*)(tb + l31 * 256 + roff) = (u32x2){lo, hi};
        }

#pragma unroll
    for (int it = 0; it < 8; ++it) {
        const int c16  = lane + 64 * it;       // 16-B chunk id in 8 KB tile
        const int nd   = c16 >> 4;             // node within tile
        const int roff = ((c16 & 15) * 16) ^ ((nd & 7) << 4);
        const uint4 v = *(const uint4*)(tb + nd * 256 + roff);
        if (nodeBase + nd < nNodes)
            *(uint4*)(pq + (size_t)nodeBase * 128 + (size_t)c16 * 8) = v;
    }
}

// ---------------------------------------------------------------------------
// Kernel B: edge MLP tail. 4 lanes per edge, 4x16-B gathers per thread.
// ---------------------------------------------------------------------------
__global__ __launch_bounds__(256) void edge_mlp(
    const int* __restrict__ e0, const int* __restrict__ e1,
    const u16* __restrict__ pq, const u16* __restrict__ w2tab,
    const float* __restrict__ b2, float* __restrict__ out, int E)
{
    const int gid = blockIdx.x * 256 + threadIdx.x;
    const int e   = gid >> 2;
    const int sub = gid & 3;
    if (e >= E) return;

    const int i = e0[e];
    const int j = e1[e];

    const uint4* pr = (const uint4*)(pq + (size_t)i * 128);
    const uint4* qr = (const uint4*)(pq + (size_t)j * 128 + 64);
    const uint4 p0 = pr[2 * sub];
    const uint4 p1 = pr[2 * sub + 1];
    const uint4 q0 = qr[2 * sub];
    const uint4 q1 = qr[2 * sub + 1];

    const uint4* wr = (const uint4*)w2tab;     // L1-hot fp16 W2
    const uint4 w0 = wr[2 * sub];
    const uint4 w1 = wr[2 * sub + 1];

    const u32 pw[8] = {p0.x, p0.y, p0.z, p0.w, p1.x, p1.y, p1.z, p1.w};
    const u32 qw[8] = {q0.x, q0.y, q0.z, q0.w, q1.x, q1.y, q1.z, q1.w};
    const u32 ww[8] = {w0.x, w0.y, w0.z, w0.w, w1.x, w1.y, w1.z, w1.w};
    const h16x2 hzero = (h16x2){(_Float16)0.0f, (_Float16)0.0f};

    float sum = 0.0f;
#pragma unroll
    for (int c = 0; c < 8; ++c) {
        h16x2 pp = __builtin_bit_cast(h16x2, pw[c]);
        h16x2 qq = __builtin_bit_cast(h16x2, qw[c]);
        h16x2 wc = __builtin_bit_cast(h16x2, ww[c]);
        h16x2 a  = __builtin_elementwise_max(pp + qq, hzero); // pk_add + pk_max
#if __has_builtin(__builtin_amdgcn_fdot2)
        sum = __builtin_amdgcn_fdot2(a, wc, sum, false);
#else
        sum = fmaf((float)a[0], (float)wc[0],
              fmaf((float)a[1], (float)wc[1], sum));
#endif
    }

    sum += __shfl_xor(sum, 1);
    sum += __shfl_xor(sum, 2);

    if (sub == 0) out[e] = sum + b2[0];
}

// ---------------------------------------------------------------------------
extern "C" void kernel_launch(void* const* d_in, const int* in_sizes, int n_in,
                              void* d_out, int out_size, void* d_ws, size_t ws_size,
                              hipStream_t stream) {
    const float* z  = (const float*)d_in[0];
    const int*   eg = (const int*)d_in[1];
    const float* W1 = (const float*)d_in[2];
    const float* b1 = (const float*)d_in[3];
    const float* W2 = (const float*)d_in[4];
    const float* b2 = (const float*)d_in[5];
    float* out = (float*)d_out;

    const int nNodes = in_sizes[0] / 64;   // 100000
    const int E      = in_sizes[1] / 2;    // 1000000

    u16* wtab = (u16*)d_ws;                        // 16 KB frag table + 128 B W2
    u16* pq   = (u16*)d_ws + 16384;                // nNodes*128*2 = 25.6 MB

    build_wfrag<<<dim3(33), dim3(256), 0, stream>>>(W1, W2, wtab);

    dim3 gA((nNodes + 127) / 128);         // 4 waves x 32 nodes per block
    node_mfma<<<gA, dim3(256), 0, stream>>>(z, wtab, b1, pq, nNodes);

    long long tB = (long long)E * 4;       // 4 threads per edge
    dim3 gB((unsigned)((tB + 255) / 256));
    // TELEMETRY: launched twice (idempotent). T_edge = dur_us - 122.75.
    edge_mlp<<<gB, dim3(256), 0, stream>>>(eg, eg + E, pq, wtab + 8192, b2, out, E);
    edge_mlp<<<gB, dim3(256), 0, stream>>>(eg, eg + E, pq, wtab + 8192, b2, out, E);
}

// Round 3
// 134.746 us; speedup vs baseline: 1.1416x; 1.1416x over previous
//
#include <hip/hip_runtime.h>
#include <hip/hip_bf16.h>

typedef unsigned short u16;
typedef unsigned int u32;
typedef __attribute__((ext_vector_type(8))) short bf16x8;   // 8 bf16 = 4 VGPR
typedef __attribute__((ext_vector_type(16))) float f32x16;  // 32x32 C/D frag
typedef __attribute__((ext_vector_type(2))) unsigned int u32x2;
typedef _Float16 h16x2 __attribute__((ext_vector_type(2)));

static __device__ __forceinline__ u16 f2bf(float f) {
    __hip_bfloat16 b = __float2bfloat16(f);   // RNE
    return *(u16*)&b;
}
static __device__ __forceinline__ u16 f2h(float f) {
    _Float16 h = (_Float16)f;                  // RNE
    return __builtin_bit_cast(u16, h);
}

// ---------------------------------------------------------------------------
// TELEMETRY ROUND 2: pipeline is byte-identical to R1 except node_mfma is
// launched TWICE (idempotent: deterministically recomputes pq from unchanged
// z/wtab/b1).  R2 established T_edge = 31.1 us (153.82 - 122.75).  Now
// T_node = dur_us - 122.75.  This closes the time-budget system:
//   122.75 = fill(44.5) + build + T_node + 31.1 + overhead
// Decision rule (pre-committed): T_node small -> attack edge next;
// T_node ~ 40 us -> restructure node (finer wave tiling, packed cvt).
// ---------------------------------------------------------------------------

// ---------------------------------------------------------------------------
// Kernel 0: build W1's MFMA fragment table (node-independent) + W2 as fp16.
// ---------------------------------------------------------------------------
__global__ __launch_bounds__(256) void build_wfrag(
    const float* __restrict__ W1, const float* __restrict__ W2,
    u16* __restrict__ wtab)
{
    const int flat = blockIdx.x * 256 + threadIdx.x;
    if (flat < 8192) {
        const int j    = flat & 7;
        const int lane = (flat >> 3) & 63;
        const int ks   = (flat >> 9) & 3;
        const int ct   = flat >> 11;
        const int k = ks * 16 + (lane >> 5) * 8 + j;
        const int c = ct * 32 + (lane & 31);
        const float v = (c < 64) ? W1[(size_t)k * 64 + c]
                                 : W1[(size_t)(64 + k) * 64 + (c - 64)];
        wtab[flat] = f2bf(v);
    } else if (flat < 8256) {
        wtab[flat] = f2h(W2[flat - 8192]);     // w2tab
    }
}

// ---------------------------------------------------------------------------
// Kernel A (MFMA, swapped operands): pq[n][c], c in 0..127 (fp16).
// ---------------------------------------------------------------------------
__global__ __launch_bounds__(256) void node_mfma(
    const float* __restrict__ z, const u16* __restrict__ wtab,
    const float* __restrict__ b1, u16* __restrict__ pq, int nNodes)
{
    const int lane   = threadIdx.x & 63;
    const int wave   = threadIdx.x >> 6;
    const int l31    = lane & 31;
    const int half   = lane >> 5;
    const int nodeBase = (blockIdx.x * 4 + wave) * 32;
    if (nodeBase >= nNodes) return;

    __shared__ u16 tile[4][4096];              // 8 KB per wave, wave-private

    const bf16x8* wt = (const bf16x8*)wtab;
    bf16x8 Wf[4][4];
#pragma unroll
    for (int ct = 0; ct < 4; ++ct)
#pragma unroll
        for (int ks = 0; ks < 4; ++ks)
            Wf[ct][ks] = wt[(ct * 4 + ks) * 64 + lane];

    int zrowi = nodeBase + l31;
    if (zrowi > nNodes - 1) zrowi = nNodes - 1;       // clamp (safe redundant)
    const float* zrow = z + (size_t)zrowi * 64;
    bf16x8 Zf[4];
#pragma unroll
    for (int ks = 0; ks < 4; ++ks) {
        const float4 v0 = *(const float4*)(zrow + ks * 16 + half * 8);
        const float4 v1 = *(const float4*)(zrow + ks * 16 + half * 8 + 4);
        Zf[ks][0] = (short)f2bf(v0.x); Zf[ks][1] = (short)f2bf(v0.y);
        Zf[ks][2] = (short)f2bf(v0.z); Zf[ks][3] = (short)f2bf(v0.w);
        Zf[ks][4] = (short)f2bf(v1.x); Zf[ks][5] = (short)f2bf(v1.y);
        Zf[ks][6] = (short)f2bf(v1.z); Zf[ks][7] = (short)f2bf(v1.w);
    }

    f32x16 acc[4];
#pragma unroll
    for (int ct = 0; ct < 2; ++ct)
#pragma unroll
        for (int g = 0; g < 4; ++g) {
            const float4 bv = *(const float4*)(b1 + ct * 32 + g * 8 + half * 4);
            acc[ct][4 * g + 0] = bv.x; acc[ct][4 * g + 1] = bv.y;
            acc[ct][4 * g + 2] = bv.z; acc[ct][4 * g + 3] = bv.w;
        }
    acc[2] = (f32x16)(0.0f);
    acc[3] = (f32x16)(0.0f);

#pragma unroll
    for (int ks = 0; ks < 4; ++ks)
#pragma unroll
        for (int ct = 0; ct < 4; ++ct)
            acc[ct] = __builtin_amdgcn_mfma_f32_32x32x16_bf16(
                Wf[ct][ks], Zf[ks], acc[ct], 0, 0, 0);

    char* tb = (char*)&tile[wave][0];
#pragma unroll
    for (int ct = 0; ct < 4; ++ct)
#pragma unroll
        for (int g = 0; g < 4; ++g) {
            const u32 lo = (u32)f2h(acc[ct][4 * g + 0]) |
                           ((u32)f2h(acc[ct][4 * g + 1]) << 16);
            const u32 hi = (u32)f2h(acc[ct][4 * g + 2]) |
                           ((u32)f2h(acc[ct][4 * g + 3]) << 16);
            const int roff = (ct * 64 + g * 16 + half * 8) ^ ((l31 & 7) << 4);
            *(u32x2*)(tb + l31 * 256 + roff) = (u32x2){lo, hi};
        }

#pragma unroll
    for (int it = 0; it < 8; ++it) {
        const int c16  = lane + 64 * it;       // 16-B chunk id in 8 KB tile
        const int nd   = c16 >> 4;             // node within tile
        const int roff = ((c16 & 15) * 16) ^ ((nd & 7) << 4);
        const uint4 v = *(const uint4*)(tb + nd * 256 + roff);
        if (nodeBase + nd < nNodes)
            *(uint4*)(pq + (size_t)nodeBase * 128 + (size_t)c16 * 8) = v;
    }
}

// ---------------------------------------------------------------------------
// Kernel B: edge MLP tail. 4 lanes per edge, 4x16-B gathers per thread.
// ---------------------------------------------------------------------------
__global__ __launch_bounds__(256) void edge_mlp(
    const int* __restrict__ e0, const int* __restrict__ e1,
    const u16* __restrict__ pq, const u16* __restrict__ w2tab,
    const float* __restrict__ b2, float* __restrict__ out, int E)
{
    const int gid = blockIdx.x * 256 + threadIdx.x;
    const int e   = gid >> 2;
    const int sub = gid & 3;
    if (e >= E) return;

    const int i = e0[e];
    const int j = e1[e];

    const uint4* pr = (const uint4*)(pq + (size_t)i * 128);
    const uint4* qr = (const uint4*)(pq + (size_t)j * 128 + 64);
    const uint4 p0 = pr[2 * sub];
    const uint4 p1 = pr[2 * sub + 1];
    const uint4 q0 = qr[2 * sub];
    const uint4 q1 = qr[2 * sub + 1];

    const uint4* wr = (const uint4*)w2tab;     // L1-hot fp16 W2
    const uint4 w0 = wr[2 * sub];
    const uint4 w1 = wr[2 * sub + 1];

    const u32 pw[8] = {p0.x, p0.y, p0.z, p0.w, p1.x, p1.y, p1.z, p1.w};
    const u32 qw[8] = {q0.x, q0.y, q0.z, q0.w, q1.x, q1.y, q1.z, q1.w};
    const u32 ww[8] = {w0.x, w0.y, w0.z, w0.w, w1.x, w1.y, w1.z, w1.w};
    const h16x2 hzero = (h16x2){(_Float16)0.0f, (_Float16)0.0f};

    float sum = 0.0f;
#pragma unroll
    for (int c = 0; c < 8; ++c) {
        h16x2 pp = __builtin_bit_cast(h16x2, pw[c]);
        h16x2 qq = __builtin_bit_cast(h16x2, qw[c]);
        h16x2 wc = __builtin_bit_cast(h16x2, ww[c]);
        h16x2 a  = __builtin_elementwise_max(pp + qq, hzero); // pk_add + pk_max
#if __has_builtin(__builtin_amdgcn_fdot2)
        sum = __builtin_amdgcn_fdot2(a, wc, sum, false);
#else
        sum = fmaf((float)a[0], (float)wc[0],
              fmaf((float)a[1], (float)wc[1], sum));
#endif
    }

    sum += __shfl_xor(sum, 1);
    sum += __shfl_xor(sum, 2);

    if (sub == 0) out[e] = sum + b2[0];
}

// ---------------------------------------------------------------------------
extern "C" void kernel_launch(void* const* d_in, const int* in_sizes, int n_in,
                              void* d_out, int out_size, void* d_ws, size_t ws_size,
                              hipStream_t stream) {
    const float* z  = (const float*)d_in[0];
    const int*   eg = (const int*)d_in[1];
    const float* W1 = (const float*)d_in[2];
    const float* b1 = (const float*)d_in[3];
    const float* W2 = (const float*)d_in[4];
    const float* b2 = (const float*)d_in[5];
    float* out = (float*)d_out;

    const int nNodes = in_sizes[0] / 64;   // 100000
    const int E      = in_sizes[1] / 2;    // 1000000

    u16* wtab = (u16*)d_ws;                        // 16 KB frag table + 128 B W2
    u16* pq   = (u16*)d_ws + 16384;                // nNodes*128*2 = 25.6 MB

    build_wfrag<<<dim3(33), dim3(256), 0, stream>>>(W1, W2, wtab);

    dim3 gA((nNodes + 127) / 128);         // 4 waves x 32 nodes per block
    // TELEMETRY: launched twice (idempotent). T_node = dur_us - 122.75.
    node_mfma<<<gA, dim3(256), 0, stream>>>(z, wtab, b1, pq, nNodes);
    node_mfma<<<gA, dim3(256), 0, stream>>>(z, wtab, b1, pq, nNodes);

    long long tB = (long long)E * 4;       // 4 threads per edge
    dim3 gB((unsigned)((tB + 255) / 256));
    edge_mlp<<<gB, dim3(256), 0, stream>>>(eg, eg + E, pq, wtab + 8192, b2, out, E);
}

// Round 4
// 121.330 us; speedup vs baseline: 1.2678x; 1.1106x over previous
//
#include <hip/hip_runtime.h>
#include <hip/hip_bf16.h>

typedef unsigned short u16;
typedef unsigned int u32;
typedef __attribute__((ext_vector_type(8))) short bf16x8;   // 8 bf16 = 4 VGPR
typedef __attribute__((ext_vector_type(8))) float f32x8;    // half of 32x32 C/D
typedef __attribute__((ext_vector_type(2))) unsigned int u32x2;
typedef _Float16 h16x2 __attribute__((ext_vector_type(2)));

static __device__ __forceinline__ u16 f2bf(float f) {
    __hip_bfloat16 b = __float2bfloat16(f);   // RNE
    return *(u16*)&b;
}
static __device__ __forceinline__ u16 f2h(float f) {
    _Float16 h = (_Float16)f;                  // RNE
    return __builtin_bit_cast(u16, h);
}

// ---------------------------------------------------------------------------
// Budget (R2/R3 probes): fill 44.5 | harness overhead ~34 | edge 31.1 (L3
// random-gather floor, 4M mandatory line touches) | node 12.0 (floor 8.1) |
// build ~1.  This round: node_mfma occupancy fix — split the 4 ct-quadrants
// into 2 passes (acc 32 + Wf 32 live instead of 64+64), __launch_bounds__
// (256,4) forces VGPR<=128 -> 16 waves/CU instead of 8. Wf reloaded per pass
// (L2-hot, +8KB/wave).  Everything else byte-identical to R1.
// ---------------------------------------------------------------------------

// ---------------------------------------------------------------------------
// Kernel 0: build W1's MFMA fragment table (node-independent) + W2 as fp16.
// wtab flat index = ((ct*4 + ks)*64 + lane)*8 + j  holds (bf16)
//   Wcat[k = ks*16 + (lane>>5)*8 + j][c = ct*32 + (lane&31)]
// ---------------------------------------------------------------------------
__global__ __launch_bounds__(256) void build_wfrag(
    const float* __restrict__ W1, const float* __restrict__ W2,
    u16* __restrict__ wtab)
{
    const int flat = blockIdx.x * 256 + threadIdx.x;
    if (flat < 8192) {
        const int j    = flat & 7;
        const int lane = (flat >> 3) & 63;
        const int ks   = (flat >> 9) & 3;
        const int ct   = flat >> 11;
        const int k = ks * 16 + (lane >> 5) * 8 + j;
        const int c = ct * 32 + (lane & 31);
        const float v = (c < 64) ? W1[(size_t)k * 64 + c]
                                 : W1[(size_t)(64 + k) * 64 + (c - 64)];
        wtab[flat] = f2bf(v);
    } else if (flat < 8256) {
        wtab[flat] = f2h(W2[flat - 8192]);     // w2tab
    }
}

// ---------------------------------------------------------------------------
// Kernel A (MFMA, swapped operands, 2-pass): pq[n][c], c in 0..127 (fp16).
//   A = Wcat fragment (M = c), B = z fragment (N = node).
// D layout: col(lane&31)=node, row=(reg&3)+8*(reg>>2)+4*half = c within tile.
// Pass p covers ct = 2p, 2p+1 (64 c-values): load Wf[2][4], init acc[2] with
// bias, 8 MFMA, pack+swizzle into the wave-private LDS tile. After both
// passes: coalesced readback + 8x dwordx4 global stores.
// ---------------------------------------------------------------------------
__global__ __launch_bounds__(256, 4) void node_mfma(
    const float* __restrict__ z, const u16* __restrict__ wtab,
    const float* __restrict__ b1, u16* __restrict__ pq, int nNodes)
{
    const int lane   = threadIdx.x & 63;
    const int wave   = threadIdx.x >> 6;
    const int l31    = lane & 31;
    const int half   = lane >> 5;
    const int nodeBase = (blockIdx.x * 4 + wave) * 32;
    if (nodeBase >= nNodes) return;

    __shared__ u16 tile[4][4096];              // 8 KB per wave, wave-private

    // ---- B fragments (loaded once): Zf[ks][j] = z[nodeBase+l31][ks*16+half*8+j]
    int zrowi = nodeBase + l31;
    if (zrowi > nNodes - 1) zrowi = nNodes - 1;       // clamp (safe redundant)
    const float* zrow = z + (size_t)zrowi * 64;
    bf16x8 Zf[4];
#pragma unroll
    for (int ks = 0; ks < 4; ++ks) {
        const float4 v0 = *(const float4*)(zrow + ks * 16 + half * 8);
        const float4 v1 = *(const float4*)(zrow + ks * 16 + half * 8 + 4);
        Zf[ks][0] = (short)f2bf(v0.x); Zf[ks][1] = (short)f2bf(v0.y);
        Zf[ks][2] = (short)f2bf(v0.z); Zf[ks][3] = (short)f2bf(v0.w);
        Zf[ks][4] = (short)f2bf(v1.x); Zf[ks][5] = (short)f2bf(v1.y);
        Zf[ks][6] = (short)f2bf(v1.z); Zf[ks][7] = (short)f2bf(v1.w);
    }

    const bf16x8* wt = (const bf16x8*)wtab;
    char* tb = (char*)&tile[wave][0];

    // ---- two passes of 2 ct-quadrants each (halves live acc+Wf VGPRs)
    for (int pass = 0; pass < 2; ++pass) {
        const int ct0 = 2 * pass;

        bf16x8 Wf[2][4];
#pragma unroll
        for (int c2 = 0; c2 < 2; ++c2)
#pragma unroll
            for (int ks = 0; ks < 4; ++ks)
                Wf[c2][ks] = wt[((ct0 + c2) * 4 + ks) * 64 + lane];

        // acc init: bias on P cols (ct<2), zero on Q cols
        f32x8 acc[2][2];                       // [c2][reghalf 0..7 / 8..15]
#pragma unroll
        for (int c2 = 0; c2 < 2; ++c2) {
            const int ct = ct0 + c2;
            if (ct < 2) {
#pragma unroll
                for (int g = 0; g < 4; ++g) {
                    const float4 bv =
                        *(const float4*)(b1 + ct * 32 + g * 8 + half * 4);
                    acc[c2][g >> 1][4 * (g & 1) + 0] = bv.x;
                    acc[c2][g >> 1][4 * (g & 1) + 1] = bv.y;
                    acc[c2][g >> 1][4 * (g & 1) + 2] = bv.z;
                    acc[c2][g >> 1][4 * (g & 1) + 3] = bv.w;
                }
            } else {
                acc[c2][0] = (f32x8)(0.0f);
                acc[c2][1] = (f32x8)(0.0f);
            }
        }

        // MFMA: reassemble f32x16 view per c2 (compiler keeps in regs)
#pragma unroll
        for (int c2 = 0; c2 < 2; ++c2) {
            typedef __attribute__((ext_vector_type(16))) float f32x16;
            f32x16 a;
#pragma unroll
            for (int r = 0; r < 8; ++r) { a[r] = acc[c2][0][r]; a[8 + r] = acc[c2][1][r]; }
#pragma unroll
            for (int ks = 0; ks < 4; ++ks)
                a = __builtin_amdgcn_mfma_f32_32x32x16_bf16(
                    Wf[c2][ks], Zf[ks], a, 0, 0, 0);
#pragma unroll
            for (int r = 0; r < 8; ++r) { acc[c2][0][r] = a[r]; acc[c2][1][r] = a[8 + r]; }
        }

        // pack 4 consecutive c -> 8 B, swizzled ds_write_b64 (wave-private)
#pragma unroll
        for (int c2 = 0; c2 < 2; ++c2)
#pragma unroll
            for (int g = 0; g < 4; ++g) {
                const float f0 = acc[c2][g >> 1][4 * (g & 1) + 0];
                const float f1 = acc[c2][g >> 1][4 * (g & 1) + 1];
                const float f2 = acc[c2][g >> 1][4 * (g & 1) + 2];
                const float f3 = acc[c2][g >> 1][4 * (g & 1) + 3];
                const u32 lo = (u32)f2h(f0) | ((u32)f2h(f1) << 16);
                const u32 hi = (u32)f2h(f2) | ((u32)f2h(f3) << 16);
                const int roff = ((ct0 + c2) * 64 + g * 16 + half * 8)
                                 ^ ((l31 & 7) << 4);
                *(u32x2*)(tb + l31 * 256 + roff) = (u32x2){lo, hi};
            }
    }

    // ---- coalesced readback + 1 KB/instr global stores
#pragma unroll
    for (int it = 0; it < 8; ++it) {
        const int c16  = lane + 64 * it;       // 16-B chunk id in 8 KB tile
        const int nd   = c16 >> 4;             // node within tile
        const int roff = ((c16 & 15) * 16) ^ ((nd & 7) << 4);
        const uint4 v = *(const uint4*)(tb + nd * 256 + roff);
        if (nodeBase + nd < nNodes)
            *(uint4*)(pq + (size_t)nodeBase * 128 + (size_t)c16 * 8) = v;
    }
}

// ---------------------------------------------------------------------------
// Kernel B: edge MLP tail. 4 lanes per edge, 4x16-B gathers per thread.
// At its L3 random-gather floor (31.1 us, 8.3 TB/s effective) — unchanged.
// ---------------------------------------------------------------------------
__global__ __launch_bounds__(256) void edge_mlp(
    const int* __restrict__ e0, const int* __restrict__ e1,
    const u16* __restrict__ pq, const u16* __restrict__ w2tab,
    const float* __restrict__ b2, float* __restrict__ out, int E)
{
    const int gid = blockIdx.x * 256 + threadIdx.x;
    const int e   = gid >> 2;
    const int sub = gid & 3;
    if (e >= E) return;

    const int i = e0[e];
    const int j = e1[e];

    const uint4* pr = (const uint4*)(pq + (size_t)i * 128);
    const uint4* qr = (const uint4*)(pq + (size_t)j * 128 + 64);
    const uint4 p0 = pr[2 * sub];
    const uint4 p1 = pr[2 * sub + 1];
    const uint4 q0 = qr[2 * sub];
    const uint4 q1 = qr[2 * sub + 1];

    const uint4* wr = (const uint4*)w2tab;     // L1-hot fp16 W2
    const uint4 w0 = wr[2 * sub];
    const uint4 w1 = wr[2 * sub + 1];

    const u32 pw[8] = {p0.x, p0.y, p0.z, p0.w, p1.x, p1.y, p1.z, p1.w};
    const u32 qw[8] = {q0.x, q0.y, q0.z, q0.w, q1.x, q1.y, q1.z, q1.w};
    const u32 ww[8] = {w0.x, w0.y, w0.z, w0.w, w1.x, w1.y, w1.z, w1.w};
    const h16x2 hzero = (h16x2){(_Float16)0.0f, (_Float16)0.0f};

    float sum = 0.0f;
#pragma unroll
    for (int c = 0; c < 8; ++c) {
        h16x2 pp = __builtin_bit_cast(h16x2, pw[c]);
        h16x2 qq = __builtin_bit_cast(h16x2, qw[c]);
        h16x2 wc = __builtin_bit_cast(h16x2, ww[c]);
        h16x2 a  = __builtin_elementwise_max(pp + qq, hzero); // pk_add + pk_max
#if __has_builtin(__builtin_amdgcn_fdot2)
        sum = __builtin_amdgcn_fdot2(a, wc, sum, false);
#else
        sum = fmaf((float)a[0], (float)wc[0],
              fmaf((float)a[1], (float)wc[1], sum));
#endif
    }

    sum += __shfl_xor(sum, 1);
    sum += __shfl_xor(sum, 2);

    if (sub == 0) out[e] = sum + b2[0];
}

// ---------------------------------------------------------------------------
extern "C" void kernel_launch(void* const* d_in, const int* in_sizes, int n_in,
                              void* d_out, int out_size, void* d_ws, size_t ws_size,
                              hipStream_t stream) {
    const float* z  = (const float*)d_in[0];
    const int*   eg = (const int*)d_in[1];
    const float* W1 = (const float*)d_in[2];
    const float* b1 = (const float*)d_in[3];
    const float* W2 = (const float*)d_in[4];
    const float* b2 = (const float*)d_in[5];
    float* out = (float*)d_out;

    const int nNodes = in_sizes[0] / 64;   // 100000
    const int E      = in_sizes[1] / 2;    // 1000000

    u16* wtab = (u16*)d_ws;                        // 16 KB frag table + 128 B W2
    u16* pq   = (u16*)d_ws + 16384;                // nNodes*128*2 = 25.6 MB

    build_wfrag<<<dim3(33), dim3(256), 0, stream>>>(W1, W2, wtab);

    dim3 gA((nNodes + 127) / 128);         // 4 waves x 32 nodes per block
    node_mfma<<<gA, dim3(256), 0, stream>>>(z, wtab, b1, pq, nNodes);

    long long tB = (long long)E * 4;       // 4 threads per edge
    dim3 gB((unsigned)((tB + 255) / 256));
    edge_mlp<<<gB, dim3(256), 0, stream>>>(eg, eg + E, pq, wtab + 8192, b2, out, E);
}

// Round 5
// 120.591 us; speedup vs baseline: 1.2756x; 1.0061x over previous
//
#include <hip/hip_runtime.h>
#include <hip/hip_bf16.h>

typedef unsigned short u16;
typedef unsigned int u32;
typedef __attribute__((ext_vector_type(8))) short bf16x8;   // 8 bf16 = 4 VGPR
typedef __attribute__((ext_vector_type(8))) float f32x8;    // half of 32x32 C/D
typedef __attribute__((ext_vector_type(2))) unsigned int u32x2;
typedef _Float16 h16x2 __attribute__((ext_vector_type(2)));

static __device__ __forceinline__ u16 f2bf(float f) {
    __hip_bfloat16 b = __float2bfloat16(f);   // RNE
    return *(u16*)&b;
}
static __device__ __forceinline__ u16 f2h(float f) {
    _Float16 h = (_Float16)f;                  // RNE
    return __builtin_bit_cast(u16, h);
}

// 16-B direct global->LDS (HW writes to lds base + lane*16; gsrc is per-lane)
static __device__ __forceinline__ void gload_lds16(const void* g, void* l) {
    __builtin_amdgcn_global_load_lds(
        (const __attribute__((address_space(1))) unsigned int*)g,
        (__attribute__((address_space(3))) unsigned int*)l,
        16, 0, 0);
}

// ---------------------------------------------------------------------------
// Budget (R2-R4 probes): fill 44.5 | harness overhead ~34 | edge 31.1 (L3
// random-gather floor; concurrency restructure was null) | node 10.6 | build 1.
// R5 theory: the poison fill evicts L3 each iter -> z is HBM-cold, and node's
// per-lane 256-B-strided 16-B loads fetch each 64-B z line up to 4x from HBM
// (pieces consumed by different instructions). Fix: stage z per wave with 8x
// global_load_lds (contiguous 1-KB bursts, single-fetch), source pre-swizzled
// (b ^= (row&7)<<4) so the linear LDS write yields the bank-spread layout the
// fragment reads expect (both-sides-or-neither). z-stage reuses the output
// tile LDS (Zf is in regs before the epilogue overwrites it).
// ---------------------------------------------------------------------------

// ---------------------------------------------------------------------------
// Kernel 0: build W1's MFMA fragment table (node-independent) + W2 as fp16.
// wtab flat index = ((ct*4 + ks)*64 + lane)*8 + j  holds (bf16)
//   Wcat[k = ks*16 + (lane>>5)*8 + j][c = ct*32 + (lane&31)]
// ---------------------------------------------------------------------------
__global__ __launch_bounds__(256) void build_wfrag(
    const float* __restrict__ W1, const float* __restrict__ W2,
    u16* __restrict__ wtab)
{
    const int flat = blockIdx.x * 256 + threadIdx.x;
    if (flat < 8192) {
        const int j    = flat & 7;
        const int lane = (flat >> 3) & 63;
        const int ks   = (flat >> 9) & 3;
        const int ct   = flat >> 11;
        const int k = ks * 16 + (lane >> 5) * 8 + j;
        const int c = ct * 32 + (lane & 31);
        const float v = (c < 64) ? W1[(size_t)k * 64 + c]
                                 : W1[(size_t)(64 + k) * 64 + (c - 64)];
        wtab[flat] = f2bf(v);
    } else if (flat < 8256) {
        wtab[flat] = f2h(W2[flat - 8192]);     // w2tab
    }
}

// ---------------------------------------------------------------------------
// Kernel A (MFMA, swapped operands, 2-pass, LDS-staged z): pq[n][c], fp16.
//   A = Wcat fragment (M = c), B = z fragment (N = node).
// D layout: col(lane&31)=node, row=(reg&3)+8*(reg>>2)+4*half = c within tile.
// LDS tile (8 KB/wave) lifecycle: [z-stage, swizzled] -> Zf regs ->
// [output pack, swizzled] -> coalesced readback/store.
// Swizzle involution (both layouts): phys(row,b) = row*256 + (b^((row&7)<<4)).
// ---------------------------------------------------------------------------
__global__ __launch_bounds__(256, 4) void node_mfma(
    const float* __restrict__ z, const u16* __restrict__ wtab,
    const float* __restrict__ b1, u16* __restrict__ pq, int nNodes)
{
    const int lane   = threadIdx.x & 63;
    const int wave   = threadIdx.x >> 6;
    const int l31    = lane & 31;
    const int half   = lane >> 5;
    const int nodeBase = (blockIdx.x * 4 + wave) * 32;
    if (nodeBase >= nNodes) return;        // nNodes % 32 == 0: active waves full

    __shared__ u16 tile[4][4096];          // 8 KB per wave, wave-private
    char* tb = (char*)&tile[wave][0];

    // ---- phase 1: stage 32 z rows (8 KB) via contiguous 1-KB global_load_lds.
    // stage s, lane t: row r = 4s + (t>>4); LDS phys byte = s*1024 + t*16
    // (linear); global source byte-in-row = ((t&15)*16) ^ ((r&7)<<4).
    const char* zbase = (const char*)(z + (size_t)nodeBase * 64);
#pragma unroll
    for (int s = 0; s < 8; ++s) {
        const int r  = 4 * s + (lane >> 4);
        const int bb = (lane & 15) * 16;
        const char* gsrc = zbase + (size_t)r * 256 + (bb ^ ((r & 7) << 4));
        gload_lds16(gsrc, tb + s * 1024);
    }
    asm volatile("s_waitcnt vmcnt(0)" ::: "memory");

    // ---- phase 2: Zf[ks][j] = z[nodeBase+l31][ks*16 + half*8 + j] from LDS
    bf16x8 Zf[4];
    const int sw = (l31 & 7) << 4;
#pragma unroll
    for (int ks = 0; ks < 4; ++ks) {
        const int col0 = ks * 64 + half * 32;          // byte col, 32-B aligned
        const float4 v0 = *(const float4*)(tb + l31 * 256 + ((col0 +  0) ^ sw));
        const float4 v1 = *(const float4*)(tb + l31 * 256 + ((col0 + 16) ^ sw));
        Zf[ks][0] = (short)f2bf(v0.x); Zf[ks][1] = (short)f2bf(v0.y);
        Zf[ks][2] = (short)f2bf(v0.z); Zf[ks][3] = (short)f2bf(v0.w);
        Zf[ks][4] = (short)f2bf(v1.x); Zf[ks][5] = (short)f2bf(v1.y);
        Zf[ks][6] = (short)f2bf(v1.z); Zf[ks][7] = (short)f2bf(v1.w);
    }

    const bf16x8* wt = (const bf16x8*)wtab;

    // ---- phase 3: two passes of 2 ct-quadrants each (halves live acc+Wf)
    for (int pass = 0; pass < 2; ++pass) {
        const int ct0 = 2 * pass;

        bf16x8 Wf[2][4];
#pragma unroll
        for (int c2 = 0; c2 < 2; ++c2)
#pragma unroll
            for (int ks = 0; ks < 4; ++ks)
                Wf[c2][ks] = wt[((ct0 + c2) * 4 + ks) * 64 + lane];

        // acc init: bias on P cols (ct<2), zero on Q cols
        f32x8 acc[2][2];                       // [c2][reghalf 0..7 / 8..15]
#pragma unroll
        for (int c2 = 0; c2 < 2; ++c2) {
            const int ct = ct0 + c2;
            if (ct < 2) {
#pragma unroll
                for (int g = 0; g < 4; ++g) {
                    const float4 bv =
                        *(const float4*)(b1 + ct * 32 + g * 8 + half * 4);
                    acc[c2][g >> 1][4 * (g & 1) + 0] = bv.x;
                    acc[c2][g >> 1][4 * (g & 1) + 1] = bv.y;
                    acc[c2][g >> 1][4 * (g & 1) + 2] = bv.z;
                    acc[c2][g >> 1][4 * (g & 1) + 3] = bv.w;
                }
            } else {
                acc[c2][0] = (f32x8)(0.0f);
                acc[c2][1] = (f32x8)(0.0f);
            }
        }

        // MFMA
#pragma unroll
        for (int c2 = 0; c2 < 2; ++c2) {
            typedef __attribute__((ext_vector_type(16))) float f32x16;
            f32x16 a;
#pragma unroll
            for (int r = 0; r < 8; ++r) { a[r] = acc[c2][0][r]; a[8 + r] = acc[c2][1][r]; }
#pragma unroll
            for (int ks = 0; ks < 4; ++ks)
                a = __builtin_amdgcn_mfma_f32_32x32x16_bf16(
                    Wf[c2][ks], Zf[ks], a, 0, 0, 0);
#pragma unroll
            for (int r = 0; r < 8; ++r) { acc[c2][0][r] = a[r]; acc[c2][1][r] = a[8 + r]; }
        }

        // pack 4 consecutive c -> 8 B, swizzled ds_write_b64 (wave-private;
        // overwrites the z-stage — Zf already lives in registers)
#pragma unroll
        for (int c2 = 0; c2 < 2; ++c2)
#pragma unroll
            for (int g = 0; g < 4; ++g) {
                const float f0 = acc[c2][g >> 1][4 * (g & 1) + 0];
                const float f1 = acc[c2][g >> 1][4 * (g & 1) + 1];
                const float f2 = acc[c2][g >> 1][4 * (g & 1) + 2];
                const float f3 = acc[c2][g >> 1][4 * (g & 1) + 3];
                const u32 lo = (u32)f2h(f0) | ((u32)f2h(f1) << 16);
                const u32 hi = (u32)f2h(f2) | ((u32)f2h(f3) << 16);
                const int roff = ((ct0 + c2) * 64 + g * 16 + half * 8)
                                 ^ ((l31 & 7) << 4);
                *(u32x2*)(tb + l31 * 256 + roff) = (u32x2){lo, hi};
            }
    }

    // ---- phase 4: coalesced readback + 1 KB/instr global stores
#pragma unroll
    for (int it = 0; it < 8; ++it) {
        const int c16  = lane + 64 * it;       // 16-B chunk id in 8 KB tile
        const int nd   = c16 >> 4;             // node within tile
        const int roff = ((c16 & 15) * 16) ^ ((nd & 7) << 4);
        const uint4 v = *(const uint4*)(tb + nd * 256 + roff);
        if (nodeBase + nd < nNodes)
            *(uint4*)(pq + (size_t)nodeBase * 128 + (size_t)c16 * 8) = v;
    }
}

// ---------------------------------------------------------------------------
// Kernel B: edge MLP tail. 4 lanes per edge, 4x16-B gathers per thread.
// At its L3 random-gather floor (31.1 us, ~8.2 TB/s effective) — unchanged.
// ---------------------------------------------------------------------------
__global__ __launch_bounds__(256) void edge_mlp(
    const int* __restrict__ e0, const int* __restrict__ e1,
    const u16* __restrict__ pq, const u16* __restrict__ w2tab,
    const float* __restrict__ b2, float* __restrict__ out, int E)
{
    const int gid = blockIdx.x * 256 + threadIdx.x;
    const int e   = gid >> 2;
    const int sub = gid & 3;
    if (e >= E) return;

    const int i = e0[e];
    const int j = e1[e];

    const uint4* pr = (const uint4*)(pq + (size_t)i * 128);
    const uint4* qr = (const uint4*)(pq + (size_t)j * 128 + 64);
    const uint4 p0 = pr[2 * sub];
    const uint4 p1 = pr[2 * sub + 1];
    const uint4 q0 = qr[2 * sub];
    const uint4 q1 = qr[2 * sub + 1];

    const uint4* wr = (const uint4*)w2tab;     // L1-hot fp16 W2
    const uint4 w0 = wr[2 * sub];
    const uint4 w1 = wr[2 * sub + 1];

    const u32 pw[8] = {p0.x, p0.y, p0.z, p0.w, p1.x, p1.y, p1.z, p1.w};
    const u32 qw[8] = {q0.x, q0.y, q0.z, q0.w, q1.x, q1.y, q1.z, q1.w};
    const u32 ww[8] = {w0.x, w0.y, w0.z, w0.w, w1.x, w1.y, w1.z, w1.w};
    const h16x2 hzero = (h16x2){(_Float16)0.0f, (_Float16)0.0f};

    float sum = 0.0f;
#pragma unroll
    for (int c = 0; c < 8; ++c) {
        h16x2 pp = __builtin_bit_cast(h16x2, pw[c]);
        h16x2 qq = __builtin_bit_cast(h16x2, qw[c]);
        h16x2 wc = __builtin_bit_cast(h16x2, ww[c]);
        h16x2 a  = __builtin_elementwise_max(pp + qq, hzero); // pk_add + pk_max
#if __has_builtin(__builtin_amdgcn_fdot2)
        sum = __builtin_amdgcn_fdot2(a, wc, sum, false);
#else
        sum = fmaf((float)a[0], (float)wc[0],
              fmaf((float)a[1], (float)wc[1], sum));
#endif
    }

    sum += __shfl_xor(sum, 1);
    sum += __shfl_xor(sum, 2);

    if (sub == 0) out[e] = sum + b2[0];
}

// ---------------------------------------------------------------------------
extern "C" void kernel_launch(void* const* d_in, const int* in_sizes, int n_in,
                              void* d_out, int out_size, void* d_ws, size_t ws_size,
                              hipStream_t stream) {
    const float* z  = (const float*)d_in[0];
    const int*   eg = (const int*)d_in[1];
    const float* W1 = (const float*)d_in[2];
    const float* b1 = (const float*)d_in[3];
    const float* W2 = (const float*)d_in[4];
    const float* b2 = (const float*)d_in[5];
    float* out = (float*)d_out;

    const int nNodes = in_sizes[0] / 64;   // 100000
    const int E      = in_sizes[1] / 2;    // 1000000

    u16* wtab = (u16*)d_ws;                        // 16 KB frag table + 128 B W2
    u16* pq   = (u16*)d_ws + 16384;                // nNodes*128*2 = 25.6 MB

    build_wfrag<<<dim3(33), dim3(256), 0, stream>>>(W1, W2, wtab);

    dim3 gA((nNodes + 127) / 128);         // 4 waves x 32 nodes per block
    node_mfma<<<gA, dim3(256), 0, stream>>>(z, wtab, b1, pq, nNodes);

    long long tB = (long long)E * 4;       // 4 threads per edge
    dim3 gB((unsigned)((tB + 255) / 256));
    edge_mlp<<<gB, dim3(256), 0, stream>>>(eg, eg + E, pq, wtab + 8192, b2, out, E);
}